// Round 7
// baseline (800.031 us; speedup 1.0000x reference)
//
#include <hip/hip_runtime.h>
#include <hip/hip_bf16.h>
#include <stdint.h>

// Problem: B=64, T=128, F=16, H=512, S=2.  All inputs fp32, lengths int32, out fp32 [64][14].
//
// R1: fixed half-staged h_l (NaN). R2: 1338us. R3: relaxed poll -> 831us (lstmk 635).
// R4: per-wave RELEASE flags (cache-maintenance storm) -> regressed 1450us.
// R5: poll-on-data sentinel protocol (no flags/drains, fire-and-forget stores) -> 656us (lstmk 465).
// R6: coalesced poll mapping (thread j owns words {j+16i}, 128B-contig per instr) -> 612us
//     (lstmk 405us, 3.16us/step). Only 13% -> request SHAPE wasn't dominant.
// R7: DECAYING poll: continuous full-sweep spinning (~2MB agent-scope line reads per sweep,
//     re-issued every ~150cy by 512 waves) saturates the LLC fabric and queue-jams the
//     producer stores themselves. Now each u64 word is re-polled ONLY while still sentinel
//     (per-lane pending mask, exec-masked retries) + s_sleep(2) backoff between retry sweeps.
//     Traffic = ~1 full sweep + geometrically-decaying stragglers; hot path (all present on
//     first sweep) unchanged -- data still lands in registers at detect time.
//
// Reshape quirk (faithful to torch): segment s', step t' uses source timestep n_t=(s'*128+t')>>1
// and embedding branch n_s=(s'*128+t')&1.

typedef __attribute__((ext_vector_type(8))) short bf16x8_t;
typedef __attribute__((ext_vector_type(4))) float f32x4_t;

#define SENT 0xAAAAAAAAu

// ---------------- workspace layout (bytes) ----------------
#define OFF_G      0u                      // bf16 [8192][2048]   33,554,432
#define OFF_TEMB   33554432u               // bf16 [8192][1024]   16,777,216
#define OFF_HH     50331648u               // bf16 [129][128][512] 16,908,288
#define OFF_WHH    67239936u               // bf16 [2048][512]     2,097,152
#define OFF_WMID   69337088u               // bf16 [2048][1024]    4,194,304
#define OFF_WC0    73531392u               // f32  [2048][8]          65,536
#define OFF_WC1    73596928u               // f32  [2048][8] (6 used) 65,536
#define OFF_BC     73662464u               // f32  [2][2048]          16,384
#define OFF_HFIN   73678848u               // f32  [64][1024]        262,144
// total ~74 MB

__device__ __forceinline__ float bf2f(uint16_t u){
  union { uint32_t i; float f; } v; v.i = ((uint32_t)u) << 16; return v.f;
}
__device__ __forceinline__ uint16_t f2b(float f){
  union { float f; uint32_t i; } v; v.f = f;
  uint32_t r = v.i + 0x7fffu + ((v.i >> 16) & 1u);  // RNE
  return (uint16_t)(r >> 16);
}
__device__ __forceinline__ float sigm(float x){ return 1.0f/(1.0f + __expf(-x)); }
__device__ __forceinline__ float tanh_(float x){
  float xc = fminf(fmaxf(x, -15.f), 15.f);
  float t = __expf(2.f*xc);
  return (t - 1.f)/(t + 1.f);
}

// ---------------- prep1: weight folding + bf16 casts ----------------
__global__ void prep1(const float* __restrict__ W_ih, const float* __restrict__ W_hh,
                      const float* __restrict__ W_is0, const float* __restrict__ b_is0,
                      const float* __restrict__ W_is1, const float* __restrict__ b_is1,
                      const float* __restrict__ b_ih, const float* __restrict__ b_hh,
                      uint16_t* __restrict__ whh_b, uint16_t* __restrict__ wmid_b,
                      float* __restrict__ wc0, float* __restrict__ wc1, float* __restrict__ bc){
  const int n = blockIdx.x;        // gate column 0..2047
  const int tid = threadIdx.x;     // 256
  __shared__ float wrow[512];
  wrow[tid]       = W_ih[(size_t)n*1536 + tid];
  wrow[tid + 256] = W_ih[(size_t)n*1536 + 256 + tid];
  for (int j = tid; j < 1024; j += 256)
    wmid_b[(size_t)n*1024 + j] = f2b(W_ih[(size_t)n*1536 + 512 + j]);
  for (int k = tid; k < 512; k += 256)
    whh_b[(size_t)n*512 + k] = f2b(W_hh[(size_t)n*512 + k]);
  __syncthreads();
  if (tid < 8){
    float s = 0.f;
    for (int k = 0; k < 512; ++k) s += wrow[k]*W_is0[k*8 + tid];
    wc0[n*8 + tid] = s;
  } else if (tid < 16){
    int c = tid - 8;
    float s = 0.f;
    if (c < 6){ for (int k = 0; k < 512; ++k) s += wrow[k]*W_is1[k*6 + c]; }
    wc1[n*8 + c] = s;              // c==6,7 stay 0 (stride-8 padding)
  } else if (tid == 16){
    float s = b_ih[n] + b_hh[n];
    for (int k = 0; k < 512; ++k) s += wrow[k]*b_is0[k];
    bc[n] = s;
  } else if (tid == 17){
    float s = b_ih[n] + b_hh[n];
    for (int k = 0; k < 512; ++k) s += wrow[k]*b_is1[k];
    bc[2048 + n] = s;
  }
}

// ---------------- prep2: h_hist[0]=h0, h_hist[1..128]=sentinel ----------------
__global__ void prep2(const float* __restrict__ h0, uint16_t* __restrict__ h_hist){
  int i = blockIdx.x*256 + threadIdx.x;   // grid 16512 -> 4,227,072 u32 words
  uint32_t* hh = (uint32_t*)h_hist;
  if (i < 32768){                          // level 0: 128 rows x 512 bf16 = 32768 u32
    int rw = i >> 8, k = (i & 255)*2;      // row = (s*64+b); both segments start at h0[b]
    uint32_t lo = f2b(h0[(size_t)(rw & 63)*512 + k]);
    uint32_t hi = f2b(h0[(size_t)(rw & 63)*512 + k + 1]);
    uint32_t w = lo | (hi << 16);
    if (w == SENT) w ^= 1u;                // can't happen (h0>=0) but cheap guard
    hh[i] = w;
  } else if (i < 4227072){
    hh[i] = SENT;
  }
}

// ---------------- tembk: timestep embedding, bf16 ----------------
__global__ void tembk(const float* __restrict__ x, uint16_t* __restrict__ temb){
  const int rid = blockIdx.x;       // (b*128 + t)
  const int k = threadIdx.x;        // 0..255
  float x0 = x[(size_t)rid*16 + 0], x1 = x[(size_t)rid*16 + 1];
  float f = __expf((float)k * (-9.210340371976184f/256.f));  // 10000^(-k/256)
  float a0 = x0*f, a1 = x1*f;
  size_t base = (size_t)rid*1024;
  temb[base + k]        = f2b(__cosf(a0));
  temb[base + 256 + k]  = f2b(__sinf(a0));
  temb[base + 512 + k]  = f2b(__cosf(a1));
  temb[base + 768 + k]  = f2b(__sinf(a1));
}

// ---------------- gemmB: G = temb[8192,1024] @ wmid[2048,1024]^T  (bf16 MFMA) ----------------
__launch_bounds__(256)
__global__ void gemmB(const uint16_t* __restrict__ temb, const uint16_t* __restrict__ wmid,
                      uint16_t* __restrict__ G){
  __shared__ __align__(16) uint16_t Al[128][72];  // 64 + 8 pad
  __shared__ __align__(16) uint16_t Bl[128][72];
  const int tid = threadIdx.x;
  const int m0 = blockIdx.x*128, n0 = blockIdx.y*128;
  const int w = tid >> 6, lane = tid & 63;
  const int q = lane >> 4, ln = lane & 15;
  const int wm = w >> 1, wn = w & 1;
  const int srow = tid >> 1, shalf = tid & 1;

  f32x4_t acc[4][4];
  #pragma unroll
  for (int a = 0; a < 4; ++a)
    #pragma unroll
    for (int b = 0; b < 4; ++b) acc[a][b] = (f32x4_t){0.f,0.f,0.f,0.f};

  for (int kb = 0; kb < 16; ++kb){
    const uint4* ga = (const uint4*)(temb + (size_t)(m0 + srow)*1024 + kb*64 + shalf*32);
    const uint4* gb = (const uint4*)(wmid + (size_t)(n0 + srow)*1024 + kb*64 + shalf*32);
    uint4 va[4], vb[4];
    #pragma unroll
    for (int i = 0; i < 4; ++i){ va[i] = ga[i]; vb[i] = gb[i]; }
    #pragma unroll
    for (int i = 0; i < 4; ++i){
      *(uint4*)&Al[srow][shalf*32 + i*8] = va[i];
      *(uint4*)&Bl[srow][shalf*32 + i*8] = vb[i];
    }
    __syncthreads();
    #pragma unroll
    for (int kc = 0; kc < 2; ++kc){
      bf16x8_t af[4], bf[4];
      #pragma unroll
      for (int mt = 0; mt < 4; ++mt) af[mt] = *(const bf16x8_t*)&Al[wm*64 + mt*16 + ln][kc*32 + q*8];
      #pragma unroll
      for (int nt = 0; nt < 4; ++nt) bf[nt] = *(const bf16x8_t*)&Bl[wn*64 + nt*16 + ln][kc*32 + q*8];
      #pragma unroll
      for (int mt = 0; mt < 4; ++mt)
        #pragma unroll
        for (int nt = 0; nt < 4; ++nt)
          acc[mt][nt] = __builtin_amdgcn_mfma_f32_16x16x32_bf16(af[mt], bf[nt], acc[mt][nt], 0, 0, 0);
    }
    __syncthreads();
  }
  #pragma unroll
  for (int mt = 0; mt < 4; ++mt)
    #pragma unroll
    for (int nt = 0; nt < 4; ++nt)
      #pragma unroll
      for (int r = 0; r < 4; ++r){
        int Mr = m0 + wm*64 + mt*16 + q*4 + r;    // C/D: col=lane&15, row=quad*4+reg (m89-verified)
        int Nc = n0 + wn*64 + nt*16 + ln;
        G[(size_t)Mr*2048 + Nc] = f2b(acc[mt][nt][r]);
      }
}

// ---------------- lstmk: persistent recurrence (R7: decaying poll-on-data) ----------------
// 128 blocks = 8 row-groups (16 rows) x 16 col-groups (32 units). blockIdx = g*8 + rr.
__launch_bounds__(256)
__global__ void lstmk(const float* __restrict__ x, const float* __restrict__ c0,
                      const int* __restrict__ lengths,
                      const uint16_t* __restrict__ whh_b, const uint16_t* __restrict__ G,
                      const float* __restrict__ wc0, const float* __restrict__ wc1,
                      const float* __restrict__ bc,
                      uint16_t* __restrict__ h_hist, float* __restrict__ hfin){
  __shared__ __align__(16) uint16_t h_l[2][16][552]; // cols 0..511 h, 512..519 xf, 520..543 zeros

  const int tid = threadIdx.x;
  const int bid = blockIdx.x;
  const int rr = bid & 7;         // row-group
  const int g  = bid >> 3;        // col-group
  const int k0 = g*32;
  const int sp = rr >> 2;         // segment of this row-group
  const int w = tid >> 6, lane = tid & 63;
  const int q = lane >> 4, ln = lane & 15;
  const int u8 = ln & 7, gh = ln >> 3;          // unit-in-octet, gate-half
  const int unit = k0 + w*8 + u8;               // this lane's hidden unit
  const int gl0 = gh*512 + unit;                // tile0 gate rows: i (gh=0), f (gh=1)
  const int gl1 = (2 + gh)*512 + unit;          // tile1 gate rows: g (gh=0), o (gh=1)

  // W_hh B-fragments resident in VGPRs/AGPRs, remapped N-tiles.
  bf16x8_t barr0[16], barr1[16];
  #pragma unroll
  for (int kc = 0; kc < 16; ++kc){
    barr0[kc] = *(const bf16x8_t*)(whh_b + (size_t)gl0*512 + kc*32 + q*8);
    barr1[kc] = *(const bf16x8_t*)(whh_b + (size_t)gl1*512 + kc*32 + q*8);
  }
  // K-extension B-fragments (xf @ Wc): rows k=512+q*8+j; only q==0 carries Wc, others zero.
  bf16x8_t e0f[2], e1f[2];
  #pragma unroll
  for (int nsI = 0; nsI < 2; ++nsI){
    bf16x8_t v0 = {0,0,0,0,0,0,0,0}, v1 = {0,0,0,0,0,0,0,0};
    if (q == 0){
      const float* wcs = nsI ? wc1 : wc0;
      #pragma unroll
      for (int j = 0; j < 8; ++j){
        ((uint16_t*)&v0)[j] = f2b(wcs[gl0*8 + j]);
        ((uint16_t*)&v1)[j] = f2b(wcs[gl1*8 + j]);
      }
    }
    e0f[nsI] = v0; e1f[nsI] = v1;
  }
  // biases per lane (per ns)
  float bc0v[2] = { bc[gl0], bc[2048 + gl0] };
  float bc1v[2] = { bc[gl1], bc[2048 + gl1] };

  // per-lane row ownership (C-layout rows q*4+r), cell state for ln<8 lanes
  int   bmr[4], lenr[4];
  float cst[4];
  #pragma unroll
  for (int r = 0; r < 4; ++r){
    int row = rr*16 + q*4 + r;
    bmr[r]  = row & 63;
    lenr[r] = lengths[bmr[r]];
    cst[r]  = c0[(size_t)bmr[r]*512 + unit];
  }

  // h staging map (coalesced): thread -> (row hm, u64 word set {j + 16*i}, stride 128B)
  const int hm = tid >> 4, j = tid & 15;
  // xf staging map (tid<128): (row xm, col xc)
  const int xm = tid >> 3, xc = tid & 7;
  const int xb = (rr*16 + xm) & 63;

  // zero the K-extension tail (cols 520..543), both buffers (NaN-in-stale-LDS guard)
  for (int idx = tid; idx < 2*16*32; idx += 256)
    h_l[idx >> 9][(idx >> 5) & 15][520 + (idx & 31)] = 0;

  for (int t = 0; t < 128; ++t){
    const int qidx = sp*128 + t;
    const int ntm = qidx >> 1;     // source timestep (reshape interleave)
    const int ns  = qidx & 1;      // embedding branch

    // --- early independent loads: G slice (C-layout, cached) + xf source ---
    uint16_t g0r[4], g1r[4];
    #pragma unroll
    for (int r = 0; r < 4; ++r){
      size_t grow = (size_t)(bmr[r]*128 + ntm)*2048;
      g0r[r] = G[grow + gl0];
      g1r[r] = G[grow + gl1];
    }
    float xv = 0.f;
    if (tid < 128){
      if (ns == 0)      xv = x[(size_t)(xb*128 + ntm)*16 + 2 + xc];
      else if (xc < 6)  xv = x[(size_t)(xb*128 + ntm)*16 + 10 + xc];
    }

    // --- decaying poll-on-data: each u64 word re-polled only while still sentinel ---
    {
      unsigned long long* hp = (unsigned long long*)
          (h_hist + ((size_t)t*128 + rr*16 + hm)*512);
      unsigned long long hv[8];
      uint32_t pend = 0xffu;
      while (true){
        #pragma unroll
        for (int i = 0; i < 8; ++i){
          if (pend & (1u << i)){
            unsigned long long v =
                __hip_atomic_load(&hp[j + 16*i], __ATOMIC_RELAXED, __HIP_MEMORY_SCOPE_AGENT);
            hv[i] = v;
            if (((uint32_t)v != SENT) & ((uint32_t)(v >> 32) != SENT))
              pend &= ~(1u << i);
          }
        }
        if (__all(pend == 0)) break;
        __builtin_amdgcn_s_sleep(2);   // ~128cy backoff between straggler retries
      }
      #pragma unroll
      for (int i = 0; i < 8; ++i)
        *(unsigned long long*)&h_l[t & 1][hm][(j + 16*i)*4] = hv[i];
    }
    if (tid < 128) h_l[t & 1][xm][512 + xc] = f2b(xv);
    __syncthreads();   // the only barrier per step (stage -> MFMA read)

    // --- gates = G + bias + [h|xf] @ [Whh|Wc]^T  (17 kc chunks) ---
    f32x4_t acc0, acc1;
    {
      float b0 = ns ? bc0v[1] : bc0v[0];
      float b1 = ns ? bc1v[1] : bc1v[0];
      #pragma unroll
      for (int r = 0; r < 4; ++r){ acc0[r] = bf2f(g0r[r]) + b0; acc1[r] = bf2f(g1r[r]) + b1; }
    }
    #pragma unroll
    for (int kc = 0; kc < 16; ++kc){
      bf16x8_t a = *(const bf16x8_t*)&h_l[t & 1][ln][kc*32 + q*8];
      acc0 = __builtin_amdgcn_mfma_f32_16x16x32_bf16(a, barr0[kc], acc0, 0, 0, 0);
      acc1 = __builtin_amdgcn_mfma_f32_16x16x32_bf16(a, barr1[kc], acc1, 0, 0, 0);
    }
    {
      bf16x8_t a = *(const bf16x8_t*)&h_l[t & 1][ln][512 + q*8];
      acc0 = __builtin_amdgcn_mfma_f32_16x16x32_bf16(a, ns ? e0f[1] : e0f[0], acc0, 0, 0, 0);
      acc1 = __builtin_amdgcn_mfma_f32_16x16x32_bf16(a, ns ? e1f[1] : e1f[0], acc1, 0, 0, 0);
    }

    // --- register gate exchange: lane ln has (i,g) for gh=0, (f,o) for gh=1 ---
    float pf[4], po[4];
    #pragma unroll
    for (int r = 0; r < 4; ++r){
      pf[r] = __shfl_xor(acc0[r], 8);
      po[r] = __shfl_xor(acc1[r], 8);
    }
    if (ln < 8){
      uint32_t hb[4]; float hF[4];
      #pragma unroll
      for (int r = 0; r < 4; ++r){
        float ig = acc0[r], fg = pf[r], gg = acc1[r], og = po[r];
        cst[r] = sigm(fg)*cst[r] + sigm(ig)*tanh_(gg);
        float h = sigm(og)*tanh_(cst[r]);
        hF[r] = h; hb[r] = (uint32_t)f2b(h);
      }
      #pragma unroll
      for (int r = 0; r < 4; ++r){
        uint32_t ph = (uint32_t)__shfl_xor((int)hb[r], 1);
        if (!(ln & 1)){
          uint32_t packed = hb[r] | (ph << 16);
          if (packed == SENT) packed ^= 1u;   // 1-ulp-at-3e-13 guard vs sentinel collision
          uint32_t* hp = (uint32_t*)(h_hist + ((size_t)(t+1)*128 + rr*16 + q*4 + r)*512 + unit);
          __hip_atomic_store(hp, packed, __ATOMIC_RELAXED, __HIP_MEMORY_SCOPE_AGENT);
        }
        if (t == lenr[r] - 1)
          hfin[(size_t)bmr[r]*1024 + sp*512 + unit] = hF[r];
      }
    }
    // no flag, no drain: the data is the flag.
  }
}

// ---------------- outk: out = sigmoid(hfin @ W_o^T + b_o) ----------------
__global__ void outk(const float* __restrict__ hfin, const float* __restrict__ W_o,
                     const float* __restrict__ b_o, float* __restrict__ out){
  __shared__ float hl[1024];
  __shared__ float red[16][17];
  const int b = blockIdx.x, tid = threadIdx.x;
  #pragma unroll
  for (int i = 0; i < 4; ++i) hl[tid + i*256] = hfin[(size_t)b*1024 + tid + i*256];
  __syncthreads();
  const int o = tid >> 4, j0 = tid & 15;
  float s = 0.f;
  if (o < 14){
    for (int j = j0; j < 1024; j += 16) s += hl[j]*W_o[(size_t)o*1024 + j];
  }
  red[o][j0] = s;
  __syncthreads();
  if (tid < 14){
    float tot = b_o[tid];
    #pragma unroll
    for (int i = 0; i < 16; ++i) tot += red[tid][i];
    out[b*14 + tid] = 1.0f/(1.0f + __expf(-tot));
  }
}

extern "C" void kernel_launch(void* const* d_in, const int* in_sizes, int n_in,
                              void* d_out, int out_size, void* d_ws, size_t ws_size,
                              hipStream_t stream){
  const float* x     = (const float*)d_in[0];
  const int*   lens  = (const int*)  d_in[1];
  const float* h0    = (const float*)d_in[2];
  const float* c0    = (const float*)d_in[3];
  const float* W_is0 = (const float*)d_in[4];
  const float* b_is0 = (const float*)d_in[5];
  const float* W_is1 = (const float*)d_in[6];
  const float* b_is1 = (const float*)d_in[7];
  const float* W_ih  = (const float*)d_in[8];
  const float* W_hh  = (const float*)d_in[9];
  const float* b_ih  = (const float*)d_in[10];
  const float* b_hh  = (const float*)d_in[11];
  const float* W_o   = (const float*)d_in[12];
  const float* b_o   = (const float*)d_in[13];
  float* out = (float*)d_out;

  char* ws = (char*)d_ws;   // needs ~74 MB
  uint16_t* G      = (uint16_t*)(ws + OFF_G);
  uint16_t* temb   = (uint16_t*)(ws + OFF_TEMB);
  uint16_t* h_hist = (uint16_t*)(ws + OFF_HH);
  uint16_t* whh_b  = (uint16_t*)(ws + OFF_WHH);
  uint16_t* wmid_b = (uint16_t*)(ws + OFF_WMID);
  float* wc0  = (float*)(ws + OFF_WC0);
  float* wc1  = (float*)(ws + OFF_WC1);
  float* bc   = (float*)(ws + OFF_BC);
  float* hfin = (float*)(ws + OFF_HFIN);

  hipLaunchKernelGGL(prep1, dim3(2048), dim3(256), 0, stream,
                     W_ih, W_hh, W_is0, b_is0, W_is1, b_is1, b_ih, b_hh,
                     whh_b, wmid_b, wc0, wc1, bc);
  hipLaunchKernelGGL(prep2, dim3(16512), dim3(256), 0, stream, h0, h_hist);
  hipLaunchKernelGGL(tembk, dim3(8192), dim3(256), 0, stream, x, temb);
  hipLaunchKernelGGL(gemmB, dim3(64, 16), dim3(256), 0, stream, temb, wmid_b, G);
  hipLaunchKernelGGL(lstmk, dim3(128), dim3(256), 0, stream,
                     x, c0, lens, whh_b, G, wc0, wc1, bc, h_hist, hfin);
  hipLaunchKernelGGL(outk, dim3(64), dim3(256), 0, stream, hfin, W_o, b_o, out);
}

// Round 8
// 710.999 us; speedup vs baseline: 1.1252x; 1.1252x over previous
//
#include <hip/hip_runtime.h>
#include <hip/hip_bf16.h>
#include <stdint.h>

// Problem: B=64, T=128, F=16, H=512, S=2.  All inputs fp32, lengths int32, out fp32 [64][14].
//
// R1: fixed half-staged h_l (NaN). R2: 1338us. R3: relaxed poll -> 831us (lstmk 635).
// R4: per-wave RELEASE flags -> regressed 1450us (cache-maintenance storm).
// R5: poll-on-data sentinel protocol -> 656us (lstmk 465).
// R6: coalesced poll mapping -> 612us (lstmk 405, 3.16us/step).
// R7: decaying poll + backoff -> REGRESSED 602us lstmk: system is DETECT-LATENCY bound,
//     not congestion bound — poll must stay hot. Reverted.
// R8: restructure for join width + locality (poll stays R6-hot):
//   - 64 blocks x 512 threads (8 waves x 8 units = 16 rows x 64 units per block).
//     Join per row-group: 16 -> 8 producers.
//   - h_hist re-laid out as contiguous 2KB per-(rr,cg) regions: consumer polls 7 remote
//     regions = 14KB with 2 coalesced 16B(2xu64) loads/thread.
//   - own 64 units bypass LLC: cell update writes them directly into next step's LDS
//     buffer (ds_write), global store kept only for remote consumers.
//   - MFMA chain split in two independent halves (dep depth 17 -> 9) + f32 add.
//   - __launch_bounds__(512,2): 8-wave block at 2 waves/SIMD, no VGPR squeeze.
//
// Reshape quirk (faithful to torch): segment s', step t' uses source timestep n_t=(s'*128+t')>>1
// and embedding branch n_s=(s'*128+t')&1.

typedef __attribute__((ext_vector_type(8))) short bf16x8_t;
typedef __attribute__((ext_vector_type(4))) float f32x4_t;

#define SENT 0xAAAAAAAAu

// ---------------- workspace layout (bytes) ----------------
#define OFF_G      0u                      // bf16 [8192][2048]   33,554,432
#define OFF_TEMB   33554432u               // bf16 [8192][1024]   16,777,216
#define OFF_HH     50331648u               // bf16 [129][8rr][8cg][16row][64u] 16,908,288
#define OFF_WHH    67239936u               // bf16 [2048][512]     2,097,152
#define OFF_WMID   69337088u               // bf16 [2048][1024]    4,194,304
#define OFF_WC0    73531392u               // f32  [2048][8]          65,536
#define OFF_WC1    73596928u               // f32  [2048][8] (6 used) 65,536
#define OFF_BC     73662464u               // f32  [2][2048]          16,384
#define OFF_HFIN   73678848u               // f32  [64][1024]        262,144
// total ~74 MB

__device__ __forceinline__ float bf2f(uint16_t u){
  union { uint32_t i; float f; } v; v.i = ((uint32_t)u) << 16; return v.f;
}
__device__ __forceinline__ uint16_t f2b(float f){
  union { float f; uint32_t i; } v; v.f = f;
  uint32_t r = v.i + 0x7fffu + ((v.i >> 16) & 1u);  // RNE
  return (uint16_t)(r >> 16);
}
__device__ __forceinline__ float sigm(float x){ return 1.0f/(1.0f + __expf(-x)); }
__device__ __forceinline__ float tanh_(float x){
  float xc = fminf(fmaxf(x, -15.f), 15.f);
  float t = __expf(2.f*xc);
  return (t - 1.f)/(t + 1.f);
}

// ---------------- prep1: weight folding + bf16 casts ----------------
__global__ void prep1(const float* __restrict__ W_ih, const float* __restrict__ W_hh,
                      const float* __restrict__ W_is0, const float* __restrict__ b_is0,
                      const float* __restrict__ W_is1, const float* __restrict__ b_is1,
                      const float* __restrict__ b_ih, const float* __restrict__ b_hh,
                      uint16_t* __restrict__ whh_b, uint16_t* __restrict__ wmid_b,
                      float* __restrict__ wc0, float* __restrict__ wc1, float* __restrict__ bc){
  const int n = blockIdx.x;        // gate column 0..2047
  const int tid = threadIdx.x;     // 256
  __shared__ float wrow[512];
  wrow[tid]       = W_ih[(size_t)n*1536 + tid];
  wrow[tid + 256] = W_ih[(size_t)n*1536 + 256 + tid];
  for (int j = tid; j < 1024; j += 256)
    wmid_b[(size_t)n*1024 + j] = f2b(W_ih[(size_t)n*1536 + 512 + j]);
  for (int k = tid; k < 512; k += 256)
    whh_b[(size_t)n*512 + k] = f2b(W_hh[(size_t)n*512 + k]);
  __syncthreads();
  if (tid < 8){
    float s = 0.f;
    for (int k = 0; k < 512; ++k) s += wrow[k]*W_is0[k*8 + tid];
    wc0[n*8 + tid] = s;
  } else if (tid < 16){
    int c = tid - 8;
    float s = 0.f;
    if (c < 6){ for (int k = 0; k < 512; ++k) s += wrow[k]*W_is1[k*6 + c]; }
    wc1[n*8 + c] = s;              // c==6,7 stay 0 (stride-8 padding)
  } else if (tid == 16){
    float s = b_ih[n] + b_hh[n];
    for (int k = 0; k < 512; ++k) s += wrow[k]*b_is0[k];
    bc[n] = s;
  } else if (tid == 17){
    float s = b_ih[n] + b_hh[n];
    for (int k = 0; k < 512; ++k) s += wrow[k]*b_is1[k];
    bc[2048 + n] = s;
  }
}

// ---------------- prep2: h_hist[0]=h0 (region layout), h_hist[1..128]=sentinel ------------
__global__ void prep2(const float* __restrict__ h0, uint16_t* __restrict__ h_hist){
  int i = blockIdx.x*256 + threadIdx.x;   // grid 16512 -> 4,227,072 u32 words
  uint32_t* hh = (uint32_t*)h_hist;
  if (i < 32768){                          // level 0: [rr][cg][row][64u] as u32 pairs
    int rr  = i >> 12;                     // 4096 words per rr
    int rem = i & 4095;
    int cg  = rem >> 9;                    // 512 words per cg
    int r2  = rem & 511;
    int row = r2 >> 5;                     // 32 words per row
    int up  = (r2 & 31)*2;                 // even unit-in-region
    int b    = (rr*16 + row) & 63;         // both segments start at h0[b]
    int unit = cg*64 + up;
    uint32_t lo = f2b(h0[(size_t)b*512 + unit]);
    uint32_t hi = f2b(h0[(size_t)b*512 + unit + 1]);
    uint32_t w = lo | (hi << 16);
    if (w == SENT) w ^= 1u;                // can't happen (h0>=0) but cheap guard
    hh[i] = w;
  } else if (i < 4227072){
    hh[i] = SENT;
  }
}

// ---------------- tembk: timestep embedding, bf16 ----------------
__global__ void tembk(const float* __restrict__ x, uint16_t* __restrict__ temb){
  const int rid = blockIdx.x;       // (b*128 + t)
  const int k = threadIdx.x;        // 0..255
  float x0 = x[(size_t)rid*16 + 0], x1 = x[(size_t)rid*16 + 1];
  float f = __expf((float)k * (-9.210340371976184f/256.f));  // 10000^(-k/256)
  float a0 = x0*f, a1 = x1*f;
  size_t base = (size_t)rid*1024;
  temb[base + k]        = f2b(__cosf(a0));
  temb[base + 256 + k]  = f2b(__sinf(a0));
  temb[base + 512 + k]  = f2b(__cosf(a1));
  temb[base + 768 + k]  = f2b(__sinf(a1));
}

// ---------------- gemmB: G = temb[8192,1024] @ wmid[2048,1024]^T  (bf16 MFMA) ----------------
__launch_bounds__(256)
__global__ void gemmB(const uint16_t* __restrict__ temb, const uint16_t* __restrict__ wmid,
                      uint16_t* __restrict__ G){
  __shared__ __align__(16) uint16_t Al[128][72];  // 64 + 8 pad
  __shared__ __align__(16) uint16_t Bl[128][72];
  const int tid = threadIdx.x;
  const int m0 = blockIdx.x*128, n0 = blockIdx.y*128;
  const int w = tid >> 6, lane = tid & 63;
  const int q = lane >> 4, ln = lane & 15;
  const int wm = w >> 1, wn = w & 1;
  const int srow = tid >> 1, shalf = tid & 1;

  f32x4_t acc[4][4];
  #pragma unroll
  for (int a = 0; a < 4; ++a)
    #pragma unroll
    for (int b = 0; b < 4; ++b) acc[a][b] = (f32x4_t){0.f,0.f,0.f,0.f};

  for (int kb = 0; kb < 16; ++kb){
    const uint4* ga = (const uint4*)(temb + (size_t)(m0 + srow)*1024 + kb*64 + shalf*32);
    const uint4* gb = (const uint4*)(wmid + (size_t)(n0 + srow)*1024 + kb*64 + shalf*32);
    uint4 va[4], vb[4];
    #pragma unroll
    for (int i = 0; i < 4; ++i){ va[i] = ga[i]; vb[i] = gb[i]; }
    #pragma unroll
    for (int i = 0; i < 4; ++i){
      *(uint4*)&Al[srow][shalf*32 + i*8] = va[i];
      *(uint4*)&Bl[srow][shalf*32 + i*8] = vb[i];
    }
    __syncthreads();
    #pragma unroll
    for (int kc = 0; kc < 2; ++kc){
      bf16x8_t af[4], bf[4];
      #pragma unroll
      for (int mt = 0; mt < 4; ++mt) af[mt] = *(const bf16x8_t*)&Al[wm*64 + mt*16 + ln][kc*32 + q*8];
      #pragma unroll
      for (int nt = 0; nt < 4; ++nt) bf[nt] = *(const bf16x8_t*)&Bl[wn*64 + nt*16 + ln][kc*32 + q*8];
      #pragma unroll
      for (int mt = 0; mt < 4; ++mt)
        #pragma unroll
        for (int nt = 0; nt < 4; ++nt)
          acc[mt][nt] = __builtin_amdgcn_mfma_f32_16x16x32_bf16(af[mt], bf[nt], acc[mt][nt], 0, 0, 0);
    }
    __syncthreads();
  }
  #pragma unroll
  for (int mt = 0; mt < 4; ++mt)
    #pragma unroll
    for (int nt = 0; nt < 4; ++nt)
      #pragma unroll
      for (int r = 0; r < 4; ++r){
        int Mr = m0 + wm*64 + mt*16 + q*4 + r;    // C/D: col=lane&15, row=quad*4+reg (m89-verified)
        int Nc = n0 + wn*64 + nt*16 + ln;
        G[(size_t)Mr*2048 + Nc] = f2b(acc[mt][nt][r]);
      }
}

// ---------------- lstmk: persistent recurrence (R8) ----------------
// 64 blocks x 512 threads = 8 row-groups (16 rows) x 8 col-groups (64 units). bid = cg*8 + rr.
// h_hist level layout: [rr][cg][row(16)][unit'(64)] -- 2KB contiguous per block region.
__launch_bounds__(512, 2)
__global__ void lstmk(const float* __restrict__ x, const float* __restrict__ c0,
                      const int* __restrict__ lengths,
                      const uint16_t* __restrict__ whh_b, const uint16_t* __restrict__ G,
                      const float* __restrict__ wc0, const float* __restrict__ wc1,
                      const float* __restrict__ bc,
                      uint16_t* __restrict__ h_hist, float* __restrict__ hfin){
  __shared__ __align__(16) uint16_t h_l[2][16][552]; // cols 0..511 h, 512..519 xf, 520..543 zeros

  const int tid = threadIdx.x;    // 0..511
  const int bid = blockIdx.x;
  const int rr = bid & 7;         // row-group
  const int cg = bid >> 3;        // col-group (64 units)
  const int sp = rr >> 2;         // segment of this row-group
  const int w = tid >> 6, lane = tid & 63;   // 8 waves
  const int q = lane >> 4, ln = lane & 15;
  const int u8 = ln & 7, gh = ln >> 3;          // unit-in-octet, gate-half
  const int unit = cg*64 + w*8 + u8;            // this lane's hidden unit (global col)
  const int gl0 = gh*512 + unit;                // tile0 gate rows: i (gh=0), f (gh=1)
  const int gl1 = (2 + gh)*512 + unit;          // tile1 gate rows: g (gh=0), o (gh=1)

  const int LVL = 65536;                        // elems per h_hist level

  // W_hh B-fragments resident in registers.
  bf16x8_t barr0[16], barr1[16];
  #pragma unroll
  for (int kc = 0; kc < 16; ++kc){
    barr0[kc] = *(const bf16x8_t*)(whh_b + (size_t)gl0*512 + kc*32 + q*8);
    barr1[kc] = *(const bf16x8_t*)(whh_b + (size_t)gl1*512 + kc*32 + q*8);
  }
  // K-extension B-fragments (xf @ Wc): rows k=512+q*8+j; only q==0 carries Wc, others zero.
  bf16x8_t e0f[2], e1f[2];
  #pragma unroll
  for (int nsI = 0; nsI < 2; ++nsI){
    bf16x8_t v0 = {0,0,0,0,0,0,0,0}, v1 = {0,0,0,0,0,0,0,0};
    if (q == 0){
      const float* wcs = nsI ? wc1 : wc0;
      #pragma unroll
      for (int jj = 0; jj < 8; ++jj){
        ((uint16_t*)&v0)[jj] = f2b(wcs[gl0*8 + jj]);
        ((uint16_t*)&v1)[jj] = f2b(wcs[gl1*8 + jj]);
      }
    }
    e0f[nsI] = v0; e1f[nsI] = v1;
  }
  // biases per lane (per ns)
  float bc0v[2] = { bc[gl0], bc[2048 + gl0] };
  float bc1v[2] = { bc[gl1], bc[2048 + gl1] };

  // per-lane row ownership (C-layout rows q*4+r), cell state for ln<8 lanes
  int   bmr[4], lenr[4];
  float cst[4];
  #pragma unroll
  for (int r = 0; r < 4; ++r){
    int row = rr*16 + q*4 + r;
    bmr[r]  = row & 63;
    lenr[r] = lengths[bmr[r]];
    cst[r]  = c0[(size_t)bmr[r]*512 + unit];
  }

  // Poll chunk map: 1024 16B chunks per level slice for this rr (8 regions x 128 chunks).
  // Thread handles chunks {tid, tid+512}; chunks in own cg region are skipped (LDS-local path).
  const int c1 = tid, c2 = tid + 512;
  const int cgi1 = c1 >> 7, k1 = c1 & 127, prow1 = k1 >> 3, pcol1 = (k1 & 7)*8;
  const int cgi2 = c2 >> 7, k2 = c2 & 127, prow2 = k2 >> 3, pcol2 = (k2 & 7)*8;
  const bool skip1 = (cgi1 == cg), skip2 = (cgi2 == cg);
  const size_t roff1 = (size_t)(rr*8 + cgi1)*1024 + prow1*64 + pcol1;
  const size_t roff2 = (size_t)(rr*8 + cgi2)*1024 + prow2*64 + pcol2;

  // xf staging map (tid<128): (row xm, col xc)
  const int xm = tid >> 3, xc = tid & 7;
  const int xb = (rr*16 + xm) & 63;

  // zero the K-extension tail (cols 520..543), both buffers
  for (int idx = tid; idx < 2*16*32; idx += 512)
    h_l[idx >> 9][(idx >> 5) & 15][520 + (idx & 31)] = 0;

  // init: stage OWN region of h(0) into h_l[0] (remote regions come via the t=0 poll)
  if (tid < 128){
    int c = tid, kk = c & 127, pr = kk >> 3, pc = (kk & 7)*8;
    const unsigned long long* hp = (const unsigned long long*)
        (h_hist + (size_t)(rr*8 + cg)*1024 + pr*64 + pc);
    unsigned long long a = __hip_atomic_load(&hp[0], __ATOMIC_RELAXED, __HIP_MEMORY_SCOPE_AGENT);
    unsigned long long b = __hip_atomic_load(&hp[1], __ATOMIC_RELAXED, __HIP_MEMORY_SCOPE_AGENT);
    *(unsigned long long*)&h_l[0][pr][cg*64 + pc]     = a;
    *(unsigned long long*)&h_l[0][pr][cg*64 + pc + 4] = b;
  }

  for (int t = 0; t < 128; ++t){
    const int qidx = sp*128 + t;
    const int ntm = qidx >> 1;     // source timestep (reshape interleave)
    const int ns  = qidx & 1;      // embedding branch
    const int buf = t & 1;

    // --- early independent loads: G slice (C-layout, cached) + xf source ---
    uint16_t g0r[4], g1r[4];
    #pragma unroll
    for (int r = 0; r < 4; ++r){
      size_t grow = (size_t)(bmr[r]*128 + ntm)*2048;
      g0r[r] = G[grow + gl0];
      g1r[r] = G[grow + gl1];
    }
    float xv = 0.f;
    if (tid < 128){
      if (ns == 0)      xv = x[(size_t)(xb*128 + ntm)*16 + 2 + xc];
      else if (xc < 6)  xv = x[(size_t)(xb*128 + ntm)*16 + 10 + xc];
    }

    // --- hot poll-on-data over the 7 remote regions (2x16B per thread, coalesced) ---
    {
      const unsigned long long* base = (const unsigned long long*)(h_hist + (size_t)t*LVL);
      unsigned long long a1=0, b1=0, a2=0, b2=0;
      const unsigned long long* p1 = base + (roff1 >> 2);
      const unsigned long long* p2 = base + (roff2 >> 2);
      while (true){
        bool ok = true;
        if (!skip1){
          a1 = __hip_atomic_load(&p1[0], __ATOMIC_RELAXED, __HIP_MEMORY_SCOPE_AGENT);
          b1 = __hip_atomic_load(&p1[1], __ATOMIC_RELAXED, __HIP_MEMORY_SCOPE_AGENT);
          ok &= ((uint32_t)a1 != SENT) & ((uint32_t)(a1 >> 32) != SENT)
              & ((uint32_t)b1 != SENT) & ((uint32_t)(b1 >> 32) != SENT);
        }
        if (!skip2){
          a2 = __hip_atomic_load(&p2[0], __ATOMIC_RELAXED, __HIP_MEMORY_SCOPE_AGENT);
          b2 = __hip_atomic_load(&p2[1], __ATOMIC_RELAXED, __HIP_MEMORY_SCOPE_AGENT);
          ok &= ((uint32_t)a2 != SENT) & ((uint32_t)(a2 >> 32) != SENT)
              & ((uint32_t)b2 != SENT) & ((uint32_t)(b2 >> 32) != SENT);
        }
        if (__all(ok)) break;
        __builtin_amdgcn_s_sleep(1);
      }
      if (!skip1){
        *(unsigned long long*)&h_l[buf][prow1][cgi1*64 + pcol1]     = a1;
        *(unsigned long long*)&h_l[buf][prow1][cgi1*64 + pcol1 + 4] = b1;
      }
      if (!skip2){
        *(unsigned long long*)&h_l[buf][prow2][cgi2*64 + pcol2]     = a2;
        *(unsigned long long*)&h_l[buf][prow2][cgi2*64 + pcol2 + 4] = b2;
      }
    }
    if (tid < 128) h_l[buf][xm][512 + xc] = f2b(xv);
    __syncthreads();   // the only barrier per step (stage -> MFMA read)

    // --- gates = G + bias + [h|xf] @ [Whh|Wc]^T, split into two independent chains ---
    f32x4_t a0A, a1A;
    f32x4_t a0B = (f32x4_t){0,0,0,0}, a1B = (f32x4_t){0,0,0,0};
    {
      float b0 = ns ? bc0v[1] : bc0v[0];
      float b1 = ns ? bc1v[1] : bc1v[0];
      #pragma unroll
      for (int r = 0; r < 4; ++r){ a0A[r] = bf2f(g0r[r]) + b0; a1A[r] = bf2f(g1r[r]) + b1; }
    }
    #pragma unroll
    for (int kc = 0; kc < 8; ++kc){
      bf16x8_t a = *(const bf16x8_t*)&h_l[buf][ln][kc*32 + q*8];
      a0A = __builtin_amdgcn_mfma_f32_16x16x32_bf16(a, barr0[kc], a0A, 0, 0, 0);
      a1A = __builtin_amdgcn_mfma_f32_16x16x32_bf16(a, barr1[kc], a1A, 0, 0, 0);
    }
    #pragma unroll
    for (int kc = 8; kc < 16; ++kc){
      bf16x8_t a = *(const bf16x8_t*)&h_l[buf][ln][kc*32 + q*8];
      a0B = __builtin_amdgcn_mfma_f32_16x16x32_bf16(a, barr0[kc], a0B, 0, 0, 0);
      a1B = __builtin_amdgcn_mfma_f32_16x16x32_bf16(a, barr1[kc], a1B, 0, 0, 0);
    }
    {
      bf16x8_t a = *(const bf16x8_t*)&h_l[buf][ln][512 + q*8];
      a0B = __builtin_amdgcn_mfma_f32_16x16x32_bf16(a, ns ? e0f[1] : e0f[0], a0B, 0, 0, 0);
      a1B = __builtin_amdgcn_mfma_f32_16x16x32_bf16(a, ns ? e1f[1] : e1f[0], a1B, 0, 0, 0);
    }
    f32x4_t acc0, acc1;
    #pragma unroll
    for (int r = 0; r < 4; ++r){ acc0[r] = a0A[r] + a0B[r]; acc1[r] = a1A[r] + a1B[r]; }

    // --- register gate exchange: lane ln has (i,g) for gh=0, (f,o) for gh=1 ---
    float pf[4], po[4];
    #pragma unroll
    for (int r = 0; r < 4; ++r){
      pf[r] = __shfl_xor(acc0[r], 8);
      po[r] = __shfl_xor(acc1[r], 8);
    }
    if (ln < 8){
      uint32_t hb[4]; float hF[4];
      #pragma unroll
      for (int r = 0; r < 4; ++r){
        float ig = acc0[r], fg = pf[r], gg = acc1[r], og = po[r];
        cst[r] = sigm(fg)*cst[r] + sigm(ig)*tanh_(gg);
        float h = sigm(og)*tanh_(cst[r]);
        hF[r] = h; hb[r] = (uint32_t)f2b(h);
      }
      #pragma unroll
      for (int r = 0; r < 4; ++r){
        uint32_t ph = (uint32_t)__shfl_xor((int)hb[r], 1);
        if (!(ln & 1)){
          uint32_t packed = hb[r] | (ph << 16);
          if (packed == SENT) packed ^= 1u;   // 1-ulp-at-3e-13 guard vs sentinel collision
          // local path: straight into next step's LDS buffer (own units, no LLC hop)
          *(uint32_t*)&h_l[(t+1) & 1][q*4 + r][unit] = packed;
          // remote path: fire-and-forget agent store into own contiguous region
          uint32_t* hp = (uint32_t*)(h_hist + (size_t)(t+1)*LVL
                                     + (size_t)(rr*8 + cg)*1024 + (q*4 + r)*64 + w*8 + u8);
          __hip_atomic_store(hp, packed, __ATOMIC_RELAXED, __HIP_MEMORY_SCOPE_AGENT);
        }
        if (t == lenr[r] - 1)
          hfin[(size_t)bmr[r]*1024 + sp*512 + unit] = hF[r];
      }
    }
    // no flag, no drain: the data is the flag.
  }
}

// ---------------- outk: out = sigmoid(hfin @ W_o^T + b_o) ----------------
__global__ void outk(const float* __restrict__ hfin, const float* __restrict__ W_o,
                     const float* __restrict__ b_o, float* __restrict__ out){
  __shared__ float hl[1024];
  __shared__ float red[16][17];
  const int b = blockIdx.x, tid = threadIdx.x;
  #pragma unroll
  for (int i = 0; i < 4; ++i) hl[tid + i*256] = hfin[(size_t)b*1024 + tid + i*256];
  __syncthreads();
  const int o = tid >> 4, j0 = tid & 15;
  float s = 0.f;
  if (o < 14){
    for (int j = j0; j < 1024; j += 16) s += hl[j]*W_o[(size_t)o*1024 + j];
  }
  red[o][j0] = s;
  __syncthreads();
  if (tid < 14){
    float tot = b_o[tid];
    #pragma unroll
    for (int i = 0; i < 16; ++i) tot += red[tid][i];
    out[b*14 + tid] = 1.0f/(1.0f + __expf(-tot));
  }
}

extern "C" void kernel_launch(void* const* d_in, const int* in_sizes, int n_in,
                              void* d_out, int out_size, void* d_ws, size_t ws_size,
                              hipStream_t stream){
  const float* x     = (const float*)d_in[0];
  const int*   lens  = (const int*)  d_in[1];
  const float* h0    = (const float*)d_in[2];
  const float* c0    = (const float*)d_in[3];
  const float* W_is0 = (const float*)d_in[4];
  const float* b_is0 = (const float*)d_in[5];
  const float* W_is1 = (const float*)d_in[6];
  const float* b_is1 = (const float*)d_in[7];
  const float* W_ih  = (const float*)d_in[8];
  const float* W_hh  = (const float*)d_in[9];
  const float* b_ih  = (const float*)d_in[10];
  const float* b_hh  = (const float*)d_in[11];
  const float* W_o   = (const float*)d_in[12];
  const float* b_o   = (const float*)d_in[13];
  float* out = (float*)d_out;

  char* ws = (char*)d_ws;   // needs ~74 MB
  uint16_t* G      = (uint16_t*)(ws + OFF_G);
  uint16_t* temb   = (uint16_t*)(ws + OFF_TEMB);
  uint16_t* h_hist = (uint16_t*)(ws + OFF_HH);
  uint16_t* whh_b  = (uint16_t*)(ws + OFF_WHH);
  uint16_t* wmid_b = (uint16_t*)(ws + OFF_WMID);
  float* wc0  = (float*)(ws + OFF_WC0);
  float* wc1  = (float*)(ws + OFF_WC1);
  float* bc   = (float*)(ws + OFF_BC);
  float* hfin = (float*)(ws + OFF_HFIN);

  hipLaunchKernelGGL(prep1, dim3(2048), dim3(256), 0, stream,
                     W_ih, W_hh, W_is0, b_is0, W_is1, b_is1, b_ih, b_hh,
                     whh_b, wmid_b, wc0, wc1, bc);
  hipLaunchKernelGGL(prep2, dim3(16512), dim3(256), 0, stream, h0, h_hist);
  hipLaunchKernelGGL(tembk, dim3(8192), dim3(256), 0, stream, x, temb);
  hipLaunchKernelGGL(gemmB, dim3(64, 16), dim3(256), 0, stream, temb, wmid_b, G);
  hipLaunchKernelGGL(lstmk, dim3(64), dim3(512), 0, stream,
                     x, c0, lens, whh_b, G, wc0, wc1, bc, h_hist, hfin);
  hipLaunchKernelGGL(outk, dim3(64), dim3(256), 0, stream, hfin, W_o, b_o, out);
}

// Round 9
// 599.968 us; speedup vs baseline: 1.3335x; 1.1851x over previous
//
#include <hip/hip_runtime.h>
#include <hip/hip_bf16.h>
#include <stdint.h>

// Problem: B=64, T=128, F=16, H=512, S=2.  All inputs fp32, lengths int32, out fp32 [64][14].
//
// R1: fixed half-staged h_l (NaN). R2: 1338us. R3: relaxed poll -> 831us (lstmk 635).
// R4: per-wave RELEASE flags -> regressed 1450us (cache-maintenance storm).
// R5: poll-on-data sentinel protocol -> 656us (lstmk 465).
// R6: coalesced poll mapping -> 612us (lstmk 405, 3.16us/step).  <- best
// R7: decaying poll + backoff -> regressed (detect must stay HOT).
// R8: 64 blocks x 512 thr, join 8 -> regressed 510us + 31ms outlier: spin traffic of 8 waves
//     concentrated on 64 CUs blocks the producer stores in the same CU's TA/LSU queues.
// R9: revert to R6 topology (128 blocks x 256 thr); make the exchange TRANSACTION-DENSE:
//   - h_hist laid out as contiguous 1KB per-(rr,cg) regions: [t][rr][cg16][row16][u32].
//   - consumer poll: wave w polls regions {w*4..w*4+3}; each load instruction's 64 lanes
//     cover 1KB contiguous (lane-dense) -> ~8x fewer LLC line requests/sweep vs R6,
//     same hot cadence (full re-sweep + s_sleep(1), no backoff).
//   - producer: lane-pair gather (shfl_xor 2) -> 8B stores from lanes ln%4==0;
//     32 dense transactions/block-step instead of 64 scattered 4B.
//   - everything else identical to R6 (MFMA chain, shfl cell update, one barrier/step).
//
// Reshape quirk (faithful to torch): segment s', step t' uses source timestep n_t=(s'*128+t')>>1
// and embedding branch n_s=(s'*128+t')&1.

typedef __attribute__((ext_vector_type(8))) short bf16x8_t;
typedef __attribute__((ext_vector_type(4))) float f32x4_t;

#define SENT 0xAAAAAAAAu

// ---------------- workspace layout (bytes) ----------------
#define OFF_G      0u                      // bf16 [8192][2048]   33,554,432
#define OFF_TEMB   33554432u               // bf16 [8192][1024]   16,777,216
#define OFF_HH     50331648u               // bf16 [129][8rr][16cg][16row][32u] 16,908,288
#define OFF_WHH    67239936u               // bf16 [2048][512]     2,097,152
#define OFF_WMID   69337088u               // bf16 [2048][1024]    4,194,304
#define OFF_WC0    73531392u               // f32  [2048][8]          65,536
#define OFF_WC1    73596928u               // f32  [2048][8] (6 used) 65,536
#define OFF_BC     73662464u               // f32  [2][2048]          16,384
#define OFF_HFIN   73678848u               // f32  [64][1024]        262,144
// total ~74 MB

__device__ __forceinline__ float bf2f(uint16_t u){
  union { uint32_t i; float f; } v; v.i = ((uint32_t)u) << 16; return v.f;
}
__device__ __forceinline__ uint16_t f2b(float f){
  union { float f; uint32_t i; } v; v.f = f;
  uint32_t r = v.i + 0x7fffu + ((v.i >> 16) & 1u);  // RNE
  return (uint16_t)(r >> 16);
}
__device__ __forceinline__ float sigm(float x){ return 1.0f/(1.0f + __expf(-x)); }
__device__ __forceinline__ float tanh_(float x){
  float xc = fminf(fmaxf(x, -15.f), 15.f);
  float t = __expf(2.f*xc);
  return (t - 1.f)/(t + 1.f);
}

// ---------------- prep1: weight folding + bf16 casts ----------------
__global__ void prep1(const float* __restrict__ W_ih, const float* __restrict__ W_hh,
                      const float* __restrict__ W_is0, const float* __restrict__ b_is0,
                      const float* __restrict__ W_is1, const float* __restrict__ b_is1,
                      const float* __restrict__ b_ih, const float* __restrict__ b_hh,
                      uint16_t* __restrict__ whh_b, uint16_t* __restrict__ wmid_b,
                      float* __restrict__ wc0, float* __restrict__ wc1, float* __restrict__ bc){
  const int n = blockIdx.x;        // gate column 0..2047
  const int tid = threadIdx.x;     // 256
  __shared__ float wrow[512];
  wrow[tid]       = W_ih[(size_t)n*1536 + tid];
  wrow[tid + 256] = W_ih[(size_t)n*1536 + 256 + tid];
  for (int j = tid; j < 1024; j += 256)
    wmid_b[(size_t)n*1024 + j] = f2b(W_ih[(size_t)n*1536 + 512 + j]);
  for (int k = tid; k < 512; k += 256)
    whh_b[(size_t)n*512 + k] = f2b(W_hh[(size_t)n*512 + k]);
  __syncthreads();
  if (tid < 8){
    float s = 0.f;
    for (int k = 0; k < 512; ++k) s += wrow[k]*W_is0[k*8 + tid];
    wc0[n*8 + tid] = s;
  } else if (tid < 16){
    int c = tid - 8;
    float s = 0.f;
    if (c < 6){ for (int k = 0; k < 512; ++k) s += wrow[k]*W_is1[k*6 + c]; }
    wc1[n*8 + c] = s;              // c==6,7 stay 0 (stride-8 padding)
  } else if (tid == 16){
    float s = b_ih[n] + b_hh[n];
    for (int k = 0; k < 512; ++k) s += wrow[k]*b_is0[k];
    bc[n] = s;
  } else if (tid == 17){
    float s = b_ih[n] + b_hh[n];
    for (int k = 0; k < 512; ++k) s += wrow[k]*b_is1[k];
    bc[2048 + n] = s;
  }
}

// ---------------- prep2: h_hist[0]=h0 (region layout), h_hist[1..128]=sentinel ------------
__global__ void prep2(const float* __restrict__ h0, uint16_t* __restrict__ h_hist){
  int i = blockIdx.x*256 + threadIdx.x;   // grid 16512 -> 4,227,072 u32 words
  uint32_t* hh = (uint32_t*)h_hist;
  if (i < 32768){                          // level 0: [rr][cg16][row16][u32]
    int e    = i*2;                        // even element index
    int rrcg = e >> 9;                     // 512 elems per region
    int rr   = rrcg >> 4, cg = rrcg & 15;
    int rm   = e & 511;
    int row  = rm >> 5, u = rm & 31;
    int b    = (rr*16 + row) & 63;         // both segments start at h0[b]
    int unit = cg*32 + u;
    uint32_t lo = f2b(h0[(size_t)b*512 + unit]);
    uint32_t hi = f2b(h0[(size_t)b*512 + unit + 1]);
    uint32_t wd = lo | (hi << 16);
    if (wd == SENT) wd ^= 1u;              // can't happen (h0>=0) but cheap guard
    hh[i] = wd;
  } else if (i < 4227072){
    hh[i] = SENT;
  }
}

// ---------------- tembk: timestep embedding, bf16 ----------------
__global__ void tembk(const float* __restrict__ x, uint16_t* __restrict__ temb){
  const int rid = blockIdx.x;       // (b*128 + t)
  const int k = threadIdx.x;        // 0..255
  float x0 = x[(size_t)rid*16 + 0], x1 = x[(size_t)rid*16 + 1];
  float f = __expf((float)k * (-9.210340371976184f/256.f));  // 10000^(-k/256)
  float a0 = x0*f, a1 = x1*f;
  size_t base = (size_t)rid*1024;
  temb[base + k]        = f2b(__cosf(a0));
  temb[base + 256 + k]  = f2b(__sinf(a0));
  temb[base + 512 + k]  = f2b(__cosf(a1));
  temb[base + 768 + k]  = f2b(__sinf(a1));
}

// ---------------- gemmB: G = temb[8192,1024] @ wmid[2048,1024]^T  (bf16 MFMA) ----------------
__launch_bounds__(256)
__global__ void gemmB(const uint16_t* __restrict__ temb, const uint16_t* __restrict__ wmid,
                      uint16_t* __restrict__ G){
  __shared__ __align__(16) uint16_t Al[128][72];  // 64 + 8 pad
  __shared__ __align__(16) uint16_t Bl[128][72];
  const int tid = threadIdx.x;
  const int m0 = blockIdx.x*128, n0 = blockIdx.y*128;
  const int w = tid >> 6, lane = tid & 63;
  const int q = lane >> 4, ln = lane & 15;
  const int wm = w >> 1, wn = w & 1;
  const int srow = tid >> 1, shalf = tid & 1;

  f32x4_t acc[4][4];
  #pragma unroll
  for (int a = 0; a < 4; ++a)
    #pragma unroll
    for (int b = 0; b < 4; ++b) acc[a][b] = (f32x4_t){0.f,0.f,0.f,0.f};

  for (int kb = 0; kb < 16; ++kb){
    const uint4* ga = (const uint4*)(temb + (size_t)(m0 + srow)*1024 + kb*64 + shalf*32);
    const uint4* gb = (const uint4*)(wmid + (size_t)(n0 + srow)*1024 + kb*64 + shalf*32);
    uint4 va[4], vb[4];
    #pragma unroll
    for (int i = 0; i < 4; ++i){ va[i] = ga[i]; vb[i] = gb[i]; }
    #pragma unroll
    for (int i = 0; i < 4; ++i){
      *(uint4*)&Al[srow][shalf*32 + i*8] = va[i];
      *(uint4*)&Bl[srow][shalf*32 + i*8] = vb[i];
    }
    __syncthreads();
    #pragma unroll
    for (int kc = 0; kc < 2; ++kc){
      bf16x8_t af[4], bf[4];
      #pragma unroll
      for (int mt = 0; mt < 4; ++mt) af[mt] = *(const bf16x8_t*)&Al[wm*64 + mt*16 + ln][kc*32 + q*8];
      #pragma unroll
      for (int nt = 0; nt < 4; ++nt) bf[nt] = *(const bf16x8_t*)&Bl[wn*64 + nt*16 + ln][kc*32 + q*8];
      #pragma unroll
      for (int mt = 0; mt < 4; ++mt)
        #pragma unroll
        for (int nt = 0; nt < 4; ++nt)
          acc[mt][nt] = __builtin_amdgcn_mfma_f32_16x16x32_bf16(af[mt], bf[nt], acc[mt][nt], 0, 0, 0);
    }
    __syncthreads();
  }
  #pragma unroll
  for (int mt = 0; mt < 4; ++mt)
    #pragma unroll
    for (int nt = 0; nt < 4; ++nt)
      #pragma unroll
      for (int r = 0; r < 4; ++r){
        int Mr = m0 + wm*64 + mt*16 + q*4 + r;    // C/D: col=lane&15, row=quad*4+reg (m89-verified)
        int Nc = n0 + wn*64 + nt*16 + ln;
        G[(size_t)Mr*2048 + Nc] = f2b(acc[mt][nt][r]);
      }
}

// ---------------- lstmk: persistent recurrence (R9: dense-transaction exchange) ----------------
// 128 blocks = 8 row-groups (16 rows) x 16 col-groups (32 units). blockIdx = g*8 + rr.
// h_hist level layout: [rr][cg16][row16][u32] -- 1KB contiguous per block region.
__launch_bounds__(256)
__global__ void lstmk(const float* __restrict__ x, const float* __restrict__ c0,
                      const int* __restrict__ lengths,
                      const uint16_t* __restrict__ whh_b, const uint16_t* __restrict__ G,
                      const float* __restrict__ wc0, const float* __restrict__ wc1,
                      const float* __restrict__ bc,
                      uint16_t* __restrict__ h_hist, float* __restrict__ hfin){
  __shared__ __align__(16) uint16_t h_l[2][16][552]; // cols 0..511 h, 512..519 xf, 520..543 zeros

  const int tid = threadIdx.x;
  const int bid = blockIdx.x;
  const int rr = bid & 7;         // row-group
  const int g  = bid >> 3;        // col-group
  const int k0 = g*32;
  const int sp = rr >> 2;         // segment of this row-group
  const int w = tid >> 6, lane = tid & 63;
  const int q = lane >> 4, ln = lane & 15;
  const int u8 = ln & 7, gh = ln >> 3;          // unit-in-octet, gate-half
  const int unit = k0 + w*8 + u8;               // this lane's hidden unit
  const int gl0 = gh*512 + unit;                // tile0 gate rows: i (gh=0), f (gh=1)
  const int gl1 = (2 + gh)*512 + unit;          // tile1 gate rows: g (gh=0), o (gh=1)

  const int LVL = 65536;                        // elems per h_hist level

  // W_hh B-fragments resident in registers, remapped N-tiles.
  bf16x8_t barr0[16], barr1[16];
  #pragma unroll
  for (int kc = 0; kc < 16; ++kc){
    barr0[kc] = *(const bf16x8_t*)(whh_b + (size_t)gl0*512 + kc*32 + q*8);
    barr1[kc] = *(const bf16x8_t*)(whh_b + (size_t)gl1*512 + kc*32 + q*8);
  }
  // K-extension B-fragments (xf @ Wc): rows k=512+q*8+j; only q==0 carries Wc, others zero.
  bf16x8_t e0f[2], e1f[2];
  #pragma unroll
  for (int nsI = 0; nsI < 2; ++nsI){
    bf16x8_t v0 = {0,0,0,0,0,0,0,0}, v1 = {0,0,0,0,0,0,0,0};
    if (q == 0){
      const float* wcs = nsI ? wc1 : wc0;
      #pragma unroll
      for (int jj = 0; jj < 8; ++jj){
        ((uint16_t*)&v0)[jj] = f2b(wcs[gl0*8 + jj]);
        ((uint16_t*)&v1)[jj] = f2b(wcs[gl1*8 + jj]);
      }
    }
    e0f[nsI] = v0; e1f[nsI] = v1;
  }
  // biases per lane (per ns)
  float bc0v[2] = { bc[gl0], bc[2048 + gl0] };
  float bc1v[2] = { bc[gl1], bc[2048 + gl1] };

  // per-lane row ownership (C-layout rows q*4+r), cell state for ln<8 lanes
  int   bmr[4], lenr[4];
  float cst[4];
  #pragma unroll
  for (int r = 0; r < 4; ++r){
    int row = rr*16 + q*4 + r;
    bmr[r]  = row & 63;
    lenr[r] = lengths[bmr[r]];
    cst[r]  = c0[(size_t)bmr[r]*512 + unit];
  }

  // Poll map (lane-dense): wave w polls regions w*4..w*4+3; lane covers 16B at lane*16
  // within each region -> each load instruction's 64 lanes span 1KB contiguous.
  const int prow = lane >> 2;          // 0..15 row within region
  const int pcol = (lane & 3)*8;       // elem col 0,8,16,24 (16B chunk)
  // xf staging map (tid<128): (row xm, col xc)
  const int xm = tid >> 3, xc = tid & 7;
  const int xb = (rr*16 + xm) & 63;

  // own-region store base (u64 index), lanes ln%4==0 of the ln<8 group store 8B each
  const size_t stb = ((size_t)rr*8192 + g*512);   // elems, level-relative

  // zero the K-extension tail (cols 520..543), both buffers
  for (int idx = tid; idx < 2*16*32; idx += 256)
    h_l[idx >> 9][(idx >> 5) & 15][520 + (idx & 31)] = 0;

  for (int t = 0; t < 128; ++t){
    const int qidx = sp*128 + t;
    const int ntm = qidx >> 1;     // source timestep (reshape interleave)
    const int ns  = qidx & 1;      // embedding branch
    const int buf = t & 1;

    // --- early independent loads: G slice (C-layout, cached) + xf source ---
    uint16_t g0r[4], g1r[4];
    #pragma unroll
    for (int r = 0; r < 4; ++r){
      size_t grow = (size_t)(bmr[r]*128 + ntm)*2048;
      g0r[r] = G[grow + gl0];
      g1r[r] = G[grow + gl1];
    }
    float xv = 0.f;
    if (tid < 128){
      if (ns == 0)      xv = x[(size_t)(xb*128 + ntm)*16 + 2 + xc];
      else if (xc < 6)  xv = x[(size_t)(xb*128 + ntm)*16 + 10 + xc];
    }

    // --- hot poll-on-data, lane-dense: wave w sweeps its 4 regions (4KB) per iteration ---
    {
      const unsigned long long* lvl = (const unsigned long long*)h_hist
                                      + (((size_t)t*LVL + (size_t)rr*8192) >> 2);
      unsigned long long hv[4][2];
      while (true){
        bool ok = true;
        #pragma unroll
        for (int i = 0; i < 4; ++i){
          const unsigned long long* p = lvl + ((size_t)(w*4 + i)*128 + prow*8 + (pcol >> 2));
          hv[i][0] = __hip_atomic_load(&p[0], __ATOMIC_RELAXED, __HIP_MEMORY_SCOPE_AGENT);
          hv[i][1] = __hip_atomic_load(&p[1], __ATOMIC_RELAXED, __HIP_MEMORY_SCOPE_AGENT);
          ok &= ((uint32_t)hv[i][0] != SENT) & ((uint32_t)(hv[i][0] >> 32) != SENT)
              & ((uint32_t)hv[i][1] != SENT) & ((uint32_t)(hv[i][1] >> 32) != SENT);
        }
        if (__all(ok)) break;
        __builtin_amdgcn_s_sleep(1);
      }
      #pragma unroll
      for (int i = 0; i < 4; ++i){
        int reg = w*4 + i;
        *(unsigned long long*)&h_l[buf][prow][reg*32 + pcol]     = hv[i][0];
        *(unsigned long long*)&h_l[buf][prow][reg*32 + pcol + 4] = hv[i][1];
      }
    }
    if (tid < 128) h_l[buf][xm][512 + xc] = f2b(xv);
    __syncthreads();   // the only barrier per step (stage -> MFMA read)

    // --- gates = G + bias + [h|xf] @ [Whh|Wc]^T  (17 kc chunks) ---
    f32x4_t acc0, acc1;
    {
      float b0 = ns ? bc0v[1] : bc0v[0];
      float b1 = ns ? bc1v[1] : bc1v[0];
      #pragma unroll
      for (int r = 0; r < 4; ++r){ acc0[r] = bf2f(g0r[r]) + b0; acc1[r] = bf2f(g1r[r]) + b1; }
    }
    #pragma unroll
    for (int kc = 0; kc < 16; ++kc){
      bf16x8_t a = *(const bf16x8_t*)&h_l[buf][ln][kc*32 + q*8];
      acc0 = __builtin_amdgcn_mfma_f32_16x16x32_bf16(a, barr0[kc], acc0, 0, 0, 0);
      acc1 = __builtin_amdgcn_mfma_f32_16x16x32_bf16(a, barr1[kc], acc1, 0, 0, 0);
    }
    {
      bf16x8_t a = *(const bf16x8_t*)&h_l[buf][ln][512 + q*8];
      acc0 = __builtin_amdgcn_mfma_f32_16x16x32_bf16(a, ns ? e0f[1] : e0f[0], acc0, 0, 0, 0);
      acc1 = __builtin_amdgcn_mfma_f32_16x16x32_bf16(a, ns ? e1f[1] : e1f[0], acc1, 0, 0, 0);
    }

    // --- register gate exchange: lane ln has (i,g) for gh=0, (f,o) for gh=1 ---
    float pf[4], po[4];
    #pragma unroll
    for (int r = 0; r < 4; ++r){
      pf[r] = __shfl_xor(acc0[r], 8);
      po[r] = __shfl_xor(acc1[r], 8);
    }
    if (ln < 8){
      uint32_t hb[4]; float hF[4];
      #pragma unroll
      for (int r = 0; r < 4; ++r){
        float ig = acc0[r], fg = pf[r], gg = acc1[r], og = po[r];
        cst[r] = sigm(fg)*cst[r] + sigm(ig)*tanh_(gg);
        float h = sigm(og)*tanh_(cst[r]);
        hF[r] = h; hb[r] = (uint32_t)f2b(h);
      }
      #pragma unroll
      for (int r = 0; r < 4; ++r){
        uint32_t ph = (uint32_t)__shfl_xor((int)hb[r], 1);
        uint32_t packed = hb[r] | (ph << 16);          // valid on even ln: units (u8,u8+1)
        if (packed == SENT) packed ^= 1u;              // 1-ulp-at-3e-13 guard
        uint32_t hi = (uint32_t)__shfl_xor((int)packed, 2);  // neighbor pair (u8+2,u8+3)
        if ((ln & 3) == 0){
          unsigned long long v = (unsigned long long)packed | ((unsigned long long)hi << 32);
          unsigned long long* hp = (unsigned long long*)h_hist
              + (((size_t)(t+1)*LVL + stb + (size_t)(q*4 + r)*32 + w*8 + u8) >> 2);
          __hip_atomic_store(hp, v, __ATOMIC_RELAXED, __HIP_MEMORY_SCOPE_AGENT);
        }
        if (t == lenr[r] - 1)
          hfin[(size_t)bmr[r]*1024 + sp*512 + unit] = hF[r];
      }
    }
    // no flag, no drain: the data is the flag.
  }
}

// ---------------- outk: out = sigmoid(hfin @ W_o^T + b_o) ----------------
__global__ void outk(const float* __restrict__ hfin, const float* __restrict__ W_o,
                     const float* __restrict__ b_o, float* __restrict__ out){
  __shared__ float hl[1024];
  __shared__ float red[16][17];
  const int b = blockIdx.x, tid = threadIdx.x;
  #pragma unroll
  for (int i = 0; i < 4; ++i) hl[tid + i*256] = hfin[(size_t)b*1024 + tid + i*256];
  __syncthreads();
  const int o = tid >> 4, j0 = tid & 15;
  float s = 0.f;
  if (o < 14){
    for (int j = j0; j < 1024; j += 16) s += hl[j]*W_o[(size_t)o*1024 + j];
  }
  red[o][j0] = s;
  __syncthreads();
  if (tid < 14){
    float tot = b_o[tid];
    #pragma unroll
    for (int i = 0; i < 16; ++i) tot += red[tid][i];
    out[b*14 + tid] = 1.0f/(1.0f + __expf(-tot));
  }
}

extern "C" void kernel_launch(void* const* d_in, const int* in_sizes, int n_in,
                              void* d_out, int out_size, void* d_ws, size_t ws_size,
                              hipStream_t stream){
  const float* x     = (const float*)d_in[0];
  const int*   lens  = (const int*)  d_in[1];
  const float* h0    = (const float*)d_in[2];
  const float* c0    = (const float*)d_in[3];
  const float* W_is0 = (const float*)d_in[4];
  const float* b_is0 = (const float*)d_in[5];
  const float* W_is1 = (const float*)d_in[6];
  const float* b_is1 = (const float*)d_in[7];
  const float* W_ih  = (const float*)d_in[8];
  const float* W_hh  = (const float*)d_in[9];
  const float* b_ih  = (const float*)d_in[10];
  const float* b_hh  = (const float*)d_in[11];
  const float* W_o   = (const float*)d_in[12];
  const float* b_o   = (const float*)d_in[13];
  float* out = (float*)d_out;

  char* ws = (char*)d_ws;   // needs ~74 MB
  uint16_t* G      = (uint16_t*)(ws + OFF_G);
  uint16_t* temb   = (uint16_t*)(ws + OFF_TEMB);
  uint16_t* h_hist = (uint16_t*)(ws + OFF_HH);
  uint16_t* whh_b  = (uint16_t*)(ws + OFF_WHH);
  uint16_t* wmid_b = (uint16_t*)(ws + OFF_WMID);
  float* wc0  = (float*)(ws + OFF_WC0);
  float* wc1  = (float*)(ws + OFF_WC1);
  float* bc   = (float*)(ws + OFF_BC);
  float* hfin = (float*)(ws + OFF_HFIN);

  hipLaunchKernelGGL(prep1, dim3(2048), dim3(256), 0, stream,
                     W_ih, W_hh, W_is0, b_is0, W_is1, b_is1, b_ih, b_hh,
                     whh_b, wmid_b, wc0, wc1, bc);
  hipLaunchKernelGGL(prep2, dim3(16512), dim3(256), 0, stream, h0, h_hist);
  hipLaunchKernelGGL(tembk, dim3(8192), dim3(256), 0, stream, x, temb);
  hipLaunchKernelGGL(gemmB, dim3(64, 16), dim3(256), 0, stream, temb, wmid_b, G);
  hipLaunchKernelGGL(lstmk, dim3(128), dim3(256), 0, stream,
                     x, c0, lens, whh_b, G, wc0, wc1, bc, h_hist, hfin);
  hipLaunchKernelGGL(outk, dim3(64), dim3(256), 0, stream, hfin, W_o, b_o, out);
}